// Round 7
// baseline (6857.616 us; speedup 1.0000x reference)
//
#include <hip/hip_runtime.h>

// Text2Vec: ctx[b] = cos(ctx[b] @ emb[ids[b,s]]), s = 0..8191.
// 512 independent row-chains (8 batches x 64 rows); TWO rows per wave (they
// share the E reads), 256 single-wave blocks = 1 per CU.
// Per step per row: acc = sum_j readlane(v,j)*E[j][c], ascending j, single
// accumulator, fmaf == host reference bit-exactly; v = host_cosf(acc)
// (branchless glibc cosf replica, bit-exact since R1: absmax 0.0).
// R6: the LDS read pipeline is forced with volatile asm ds_read_b32 +
// counted s_waitcnt lgkmcnt(8) + sched_barrier (compiler kept destroying it:
// VGPR=76/84/88 across R3-R5). Groups of 8 reads, 2-group lookahead (<=16
// outstanding, 4-bit lgkmcnt). lgkm domain in the loop is PURE ds_read: the
// id stream uses vector global_load_dword (vmcnt), pipelined 2 steps deep,
// drained by the per-step vmcnt(0) that guards the E DMA double-buffer.
// Previous step's cos is deferred to after the read-issue block so it covers
// the first group's LDS latency.

#define BB 8
#define SS 8192
#define DD 64

// ---- branchless bit-exact replica of glibc sysdeps/ieee754/flt-32 cosf ----
__device__ __forceinline__ float host_cosf(float y)
{
#pragma clang fp contract(off)
    const double hpi_inv = 0x1.45F306DC9C883p+23;  // 2/pi * 2^24
    const double hpi     = 0x1.921FB54442D18p0;    // pi/2
    const double c0 = 0x1p0;
    const double c1 = -0x1.ffffffd0c621cp-2;
    const double c2 = 0x1.55553e1068f19p-5;
    const double c3 = -0x1.6c087e89a359dp-10;
    const double c4 = 0x1.99343027bf8c3p-16;
    const double s1 = -0x1.555545995a603p-3;
    const double s2 = 0x1.1107605230bc4p-7;
    const double s3 = -0x1.994eb3774cf24p-13;

    const double x = (double)y;

    // reduce_fast; for |y|<pi/4 yields n=0, xr==x bitwise, cosine branch ==
    // glibc's early-out poly exactly. Inputs ~N(0,6): |y|>=120 unreachable.
    double r  = x * hpi_inv;
    int    n  = (((int)r) + 0x800000) >> 24;
    double xr = fma(-(double)n, hpi, x);

    const int  mm   = (n + 1) & 3;
    const double s  = (mm == 1 || mm == 2) ? -1.0 : 1.0;
    const bool negt = (mm & 2) != 0;

    double x2  = xr * xr;
    double x4  = x2 * x2;
    double cc2 = fma(x2, c4, c3);
    double cc1 = fma(x2, c1, c0);
    double x6  = x4 * x2;
    double cp  = fma(x4, c2, cc1);
    float fcos = (float)fma(x6, cc2, cp);
    fcos = negt ? -fcos : fcos;

    double xs  = xr * s;
    double x3  = xs * x2;
    double sp1 = fma(x2, s3, s2);
    double x7  = x3 * x2;
    double sr  = fma(x3, s1, xs);
    float fsin = (float)fma(x7, sp1, sr);

    return (n & 1) ? fsin : fcos;
}

__device__ __forceinline__ float bc(float v, int lane)
{
    return __int_as_float(__builtin_amdgcn_readlane(__float_as_int(v), lane));
}

// async DMA: 16 x 1KB linear chunks, E[id] (16 KB) -> LDS buffer (vmcnt).
// Proven layout (absmax 0.0 in R4/R5): es[j*64+c] = E[j][c].
__device__ __forceinline__ void stage_E(const float* __restrict__ emb,
                                        int id, float* buf, int lane)
{
    const float* g = emb + (size_t)(unsigned)id * (DD * DD) + lane * 4;
#pragma unroll
    for (int k = 0; k < 16; ++k) {
        __builtin_amdgcn_global_load_lds(
            (const __attribute__((address_space(1))) void*)(g + k * 256),
            (__attribute__((address_space(3))) void*)(buf + k * 256),
            16, 0, 0);
    }
}

// volatile ds_read_b32 with literal offset (compiler cannot sink/batch these)
#define DSR(i, OFF) \
    asm volatile("ds_read_b32 %0, %1 offset:" OFF : "=v"(e[i]) : "v"(a0))

#define ISSUE8(B, O0,O1,O2,O3,O4,O5,O6,O7) \
    DSR(B+0,O0); DSR(B+1,O1); DSR(B+2,O2); DSR(B+3,O3); \
    DSR(B+4,O4); DSR(B+5,O5); DSR(B+6,O6); DSR(B+7,O7)

#define WAITL(N) do { \
    asm volatile("s_waitcnt lgkmcnt(" #N ")"); \
    __builtin_amdgcn_sched_barrier(0); \
} while (0)

// 8 j-steps of both rows' chains: ascending j, single acc each (bit-exact)
#define GRP(J) do { \
    acc0 = fmaf(bc(v0,(J)+0), e[(J)+0], acc0); acc1 = fmaf(bc(v1,(J)+0), e[(J)+0], acc1); \
    acc0 = fmaf(bc(v0,(J)+1), e[(J)+1], acc0); acc1 = fmaf(bc(v1,(J)+1), e[(J)+1], acc1); \
    acc0 = fmaf(bc(v0,(J)+2), e[(J)+2], acc0); acc1 = fmaf(bc(v1,(J)+2), e[(J)+2], acc1); \
    acc0 = fmaf(bc(v0,(J)+3), e[(J)+3], acc0); acc1 = fmaf(bc(v1,(J)+3), e[(J)+3], acc1); \
    acc0 = fmaf(bc(v0,(J)+4), e[(J)+4], acc0); acc1 = fmaf(bc(v1,(J)+4), e[(J)+4], acc1); \
    acc0 = fmaf(bc(v0,(J)+5), e[(J)+5], acc0); acc1 = fmaf(bc(v1,(J)+5), e[(J)+5], acc1); \
    acc0 = fmaf(bc(v0,(J)+6), e[(J)+6], acc0); acc1 = fmaf(bc(v1,(J)+6), e[(J)+6], acc1); \
    acc0 = fmaf(bc(v0,(J)+7), e[(J)+7], acc0); acc1 = fmaf(bc(v1,(J)+7), e[(J)+7], acc1); \
} while (0)

// One chain step. A0: LDS byte addr (buffer base + lane*4) of the buffer to
// consume; ENXT: buffer to DMA-fill for the next step; IDUSE: id for that DMA
// (ready: drained by a previous vmcnt(0)); VOFF: byte offset of the id to
// fetch 2 steps ahead; IDNEXT: register receiving it (vmcnt domain).
#define STEP(A0, ENXT, IDUSE, VOFF, IDNEXT, DOCOS) do { \
    asm volatile("s_waitcnt vmcnt(0)");              /* ENXT free, E cur + ids ready */ \
    __builtin_amdgcn_sched_barrier(0); \
    stage_E(emb, IDUSE, ENXT, lane);                 /* DMA issue (vmcnt) */ \
    { unsigned voff_ = (VOFF); \
      asm volatile("global_load_dword %0, %1, %2"    /* id fetch (vmcnt) */ \
                   : "=v"(IDNEXT) : "v"(voff_), "s"(bids)); } \
    const unsigned a0 = (A0); \
    float e[DD]; \
    ISSUE8(0,  "0","256","512","768","1024","1280","1536","1792"); \
    ISSUE8(8,  "2048","2304","2560","2816","3072","3328","3584","3840"); \
    if (DOCOS) { v0 = host_cosf(acc0); v1 = host_cosf(acc1); }  /* covers latency */ \
    acc0 = 0.0f; acc1 = 0.0f; \
    WAITL(8);  ISSUE8(16, "4096","4352","4608","4864","5120","5376","5632","5888");        GRP(0); \
    WAITL(8);  ISSUE8(24, "6144","6400","6656","6912","7168","7424","7680","7936");        GRP(8); \
    WAITL(8);  ISSUE8(32, "8192","8448","8704","8960","9216","9472","9728","9984");        GRP(16); \
    WAITL(8);  ISSUE8(40, "10240","10496","10752","11008","11264","11520","11776","12032"); GRP(24); \
    WAITL(8);  ISSUE8(48, "12288","12544","12800","13056","13312","13568","13824","14080"); GRP(32); \
    WAITL(8);  ISSUE8(56, "14336","14592","14848","15104","15360","15616","15872","16128"); GRP(40); \
    WAITL(8);  GRP(48); \
    WAITL(0);  GRP(56); \
} while (0)

__global__ __launch_bounds__(64, 1)
void text2vec_kernel(const int* __restrict__ ids,
                     const float* __restrict__ emb,
                     float* __restrict__ out)
{
    __shared__ float es0[DD * DD];   // 16 KB
    __shared__ float es1[DD * DD];   // 16 KB

    // blk = rp*8 + b: all blocks of batch b share an XCD (L2-resident E)
    const int blk  = blockIdx.x;
    const int b    = blk & 7;
    const int rp   = blk >> 3;               // row pair 0..31
    const int r0   = rp * 2, r1 = rp * 2 + 1;
    const int lane = threadIdx.x;            // column c

    const int* bids = ids + b * SS;

    const unsigned lb0 = (unsigned)(uintptr_t)
        (__attribute__((address_space(3))) float*)es0 + lane * 4u;
    const unsigned lb1 = (unsigned)(uintptr_t)
        (__attribute__((address_space(3))) float*)es1 + lane * 4u;

    // prologue: es0 <- E[ids[0]]; resolve id(1), id(2) to SGPRs (no SMEM in loop)
    stage_E(emb, bids[0], es0, lane);
    int ida = bids[1];
    int idb = bids[2];
    asm volatile("" :: "s"(ida), "s"(idb));

    float v0 = (lane == r0) ? 1.0f : 0.0f;   // rows r0, r1 of identity
    float v1 = (lane == r1) ? 1.0f : 0.0f;
    float acc0 = 0.0f, acc1 = 0.0f;

    for (int s = 0; s < SS; s += 2) {
        int idn_a, idn_b;
        // step s   : consume es0, fill es1 with E[id(s+1)], fetch id(s+3)
        STEP(lb0, es1, ida, ((unsigned)(s + 3) & (SS - 1)) * 4u, idn_a, (s != 0));
        // step s+1 : consume es1, fill es0 with E[id(s+2)], fetch id(s+4)
        STEP(lb1, es0, idb, ((unsigned)(s + 4) & (SS - 1)) * 4u, idn_b, true);
        ida = idn_a;    // value id(s+3), ready after next step's vmcnt(0)
        idb = idn_b;    // value id(s+4)
    }

    // epilogue: cos of the final step's accs
    v0 = host_cosf(acc0);
    v1 = host_cosf(acc1);

    out[b * (DD * DD) + r0 * DD + lane] = v0;
    out[b * (DD * DD) + r1 * DD + lane] = v1;
}

extern "C" void kernel_launch(void* const* d_in, const int* in_sizes, int n_in,
                              void* d_out, int out_size, void* d_ws, size_t ws_size,
                              hipStream_t stream)
{
    const int*   ids = (const int*)  d_in[0];   // [B, S] int32
    const float* emb = (const float*)d_in[1];   // [V, D*D] f32
    float*       out = (float*)      d_out;     // [B, D, D] f32

    text2vec_kernel<<<dim3(BB * DD / 2), dim3(DD), 0, stream>>>(ids, emb, out);
}

// Round 8
// 5245.831 us; speedup vs baseline: 1.3073x; 1.3073x over previous
//
#include <hip/hip_runtime.h>

// Text2Vec: ctx[b] = cos(ctx[b] @ emb[ids[b,s]]), s = 0..8191.
// 512 independent row-chains (8 batches x 64 rows), one wave per (b,row),
// lane c owns column c. Per step: acc = sum_j readlane(v,j)*E[j][c] with
// ascending j, single accumulator, v_fmac (== host fmaf chain bit-exactly);
// v = host_cosf(acc) (branchless glibc cosf replica, bit-exact since R1).
//
// R7: (1) table pre-transposed+bank-swizzled into d_ws once per launch ->
// per-step E loads are 16 ds_read_b128 (was 64 b32); per-lane swizzled
// vaddrs un-permute the XOR so every lane still receives ascending-j blocks.
// (2) readlane->fmac SGPR hazard killed by rotating t0..t3 temps with the
// readlane issued 3 pairs (>=12 cyc) ahead of its consumer. (3) <=15 DS ops
// in flight (lgkmcnt is 4-bit); the only per-step lgkm wait is a free
// lgkmcnt(0). (4) e-regs double-buffered (eA/eB, asm-forced); DMA double
// buffer in LDS as R4-6. 512 waves again (2 blocks/CU).

#define BB 8
#define SS 8192
#define DD 64

typedef __attribute__((ext_vector_type(4))) float f32x4;

// ---- branchless bit-exact replica of glibc sysdeps/ieee754/flt-32 cosf ----
__device__ __forceinline__ float host_cosf(float y)
{
#pragma clang fp contract(off)
    const double hpi_inv = 0x1.45F306DC9C883p+23;  // 2/pi * 2^24
    const double hpi     = 0x1.921FB54442D18p0;    // pi/2
    const double c0 = 0x1p0;
    const double c1 = -0x1.ffffffd0c621cp-2;
    const double c2 = 0x1.55553e1068f19p-5;
    const double c3 = -0x1.6c087e89a359dp-10;
    const double c4 = 0x1.99343027bf8c3p-16;
    const double s1 = -0x1.555545995a603p-3;
    const double s2 = 0x1.1107605230bc4p-7;
    const double s3 = -0x1.994eb3774cf24p-13;

    const double x = (double)y;

    double r  = x * hpi_inv;
    int    n  = (((int)r) + 0x800000) >> 24;
    double xr = fma(-(double)n, hpi, x);

    const int  mm   = (n + 1) & 3;
    const double s  = (mm == 1 || mm == 2) ? -1.0 : 1.0;
    const bool negt = (mm & 2) != 0;

    double x2  = xr * xr;
    double x4  = x2 * x2;
    double cc2 = fma(x2, c4, c3);
    double cc1 = fma(x2, c1, c0);
    double x6  = x4 * x2;
    double cp  = fma(x4, c2, cc1);
    float fcos = (float)fma(x6, cc2, cp);
    fcos = negt ? -fcos : fcos;

    double xs  = xr * s;
    double x3  = xs * x2;
    double sp1 = fma(x2, s3, s2);
    double x7  = x3 * x2;
    double sr  = fma(x3, s1, xs);
    float fsin = (float)fma(x7, sp1, sr);

    return (n & 1) ? fsin : fcos;
}

// one-time: embT[id][c*64 + ((jb^(c&7))<<2) + jq] = emb[id][j*64+c], j=4jb+jq.
// Transposed (b128-readable per lane) + XOR quad-swizzle (bank-spread).
__global__ void transpose_kernel(const float* __restrict__ emb,
                                 float* __restrict__ embT)
{
    const int id = blockIdx.x;
    const int t  = threadIdx.x;                 // 256 threads
    const float* src = emb + (size_t)id * (DD * DD);
    float*       dst = embT + (size_t)id * (DD * DD);
#pragma unroll
    for (int k = 0; k < 16; ++k) {
        const int lin = k * 256 + t;            // j*64 + c
        const int j = lin >> 6, c = lin & 63;
        dst[(c << 6) + ((((j >> 2) ^ (c & 7))) << 2) + (j & 3)] = src[lin];
    }
}

// async DMA: 16 x (16B/lane) linear chunks, embT[id] (16 KB) -> LDS buffer
__device__ __forceinline__ void stage_T(const float* __restrict__ embT,
                                        int id, float* buf, int lane)
{
    const float* g = embT + (size_t)(unsigned)id * (DD * DD) + lane * 4;
#pragma unroll
    for (int h = 0; h < 4; ++h) {
        const float* gh = g + h * 1024;
        float* bh = buf + h * 1024;
#pragma unroll
        for (int k = 0; k < 4; ++k)
            __builtin_amdgcn_global_load_lds(
                (const __attribute__((address_space(1))) void*)(gh + k * 256),
                (__attribute__((address_space(3))) void*)(bh + k * 256),
                16, 0, 0);
    }
}

// e[K] <- 4 consecutive-j E values for this lane (swizzled vaddr a[K])
#define DSR4(EN, K, OFFS) \
    asm volatile("ds_read_b128 %0, %1 offset:" OFFS : "=v"(EN[K]) : "v"(a[K]))

// v_readlane into rotating SGPR temp (lane index literal)
#define RL(T, JL) \
    asm volatile("v_readlane_b32 %0, %1, " JL : "=s"(T) : "v"(v0))
// acc += t * e   (src0=SGPR, src1=VGPR; == fmaf(v_j, e_j, acc) bit-exactly)
#define FM(T, E) \
    asm volatile("v_fmac_f32 %0, %1, %2" : "+v"(acc) : "s"(T), "v"(E))

// 4 j-steps: consumes e[4K..4K+3] with temps t0..t3; issues readlanes 4K+3..4K+6
#define G4(EC, K, A, B, C, D) \
    RL(t3, A); FM(t0, EC[K][0]); \
    RL(t0, B); FM(t1, EC[K][1]); \
    RL(t1, C); FM(t2, EC[K][2]); \
    RL(t2, D); FM(t3, EC[K][3]);

// One chain step. EC: e-regs for this step (already loaded last step).
// EN/ENOFF: e-regs + LDS imm offset to prefetch for next step.
// DMABUF: LDS buffer to refill (the one EC was read from; reads retired per
// lgkmcnt(0)). IDREG: id for that DMA (vmcnt-drained); reloaded SOFF ahead.
#define STEP(EC, EN, ENOFF, DMABUF, IDREG, SOFF, DOCOS) do { \
    asm volatile("s_waitcnt vmcnt(0)" ::: "memory");   /* DMA(next buf)+id done */ \
    asm volatile("s_waitcnt lgkmcnt(0)" ::: "memory"); /* last step's reads retired (free) */ \
    __builtin_amdgcn_sched_barrier(0); \
    DSR4(EN,0,ENOFF); DSR4(EN,1,ENOFF); DSR4(EN,2,ENOFF); DSR4(EN,3,ENOFF); \
    DSR4(EN,4,ENOFF); DSR4(EN,5,ENOFF); DSR4(EN,6,ENOFF); DSR4(EN,7,ENOFF); \
    stage_T(embT, IDREG, DMABUF, lane); \
    { unsigned voff_ = (unsigned)(((s + (SOFF)) & (SS - 1)) * 4); \
      asm volatile("global_load_dword %0, %1, %2" \
                   : "=v"(IDREG) : "v"(voff_), "s"(bids)); } \
    if (DOCOS) v0 = host_cosf(acc);   /* overlaps the issue region above */ \
    __builtin_amdgcn_sched_barrier(0); \
    acc = 0.0f; \
    RL(t0,"0"); RL(t1,"1"); RL(t2,"2"); \
    G4(EC, 0, "3","4","5","6")     G4(EC, 1, "7","8","9","10") \
    G4(EC, 2, "11","12","13","14") G4(EC, 3, "15","16","17","18") \
    G4(EC, 4, "19","20","21","22") G4(EC, 5, "23","24","25","26") \
    G4(EC, 6, "27","28","29","30") G4(EC, 7, "31","32","33","34") \
    DSR4(EN,8,ENOFF);  DSR4(EN,9,ENOFF);  DSR4(EN,10,ENOFF); DSR4(EN,11,ENOFF); \
    DSR4(EN,12,ENOFF); DSR4(EN,13,ENOFF); DSR4(EN,14,ENOFF); DSR4(EN,15,ENOFF); \
    G4(EC, 8, "35","36","37","38") G4(EC, 9, "39","40","41","42") \
    G4(EC,10, "43","44","45","46") G4(EC,11, "47","48","49","50") \
    G4(EC,12, "51","52","53","54") G4(EC,13, "55","56","57","58") \
    G4(EC,14, "59","60","61","62") \
    RL(t3,"63"); FM(t0, EC[15][0]); FM(t1, EC[15][1]); \
    FM(t2, EC[15][2]); FM(t3, EC[15][3]); \
} while (0)

__global__ __launch_bounds__(64, 1)
void text2vec_kernel(const int* __restrict__ ids,
                     const float* __restrict__ embT,
                     float* __restrict__ out)
{
    __shared__ float es[2][DD * DD];     // 2 x 16 KB DMA double buffer

    // blk = r*8 + b: all 64 rows of chain b share an XCD (L2-resident E)
    const int blk  = blockIdx.x;
    const int b    = blk & 7;
    const int r    = blk >> 3;           // 0..63
    const int lane = threadIdx.x;        // column c

    const int* bids = ids + b * SS;

    // 16 swizzled LDS vaddrs: logical block K -> physical block K^(lane&7)
    const unsigned lb = (unsigned)(uintptr_t)
        (__attribute__((address_space(3))) float*)&es[0][0];
    unsigned a[16];
#pragma unroll
    for (int k = 0; k < 16; ++k)
        a[k] = lb + (unsigned)lane * 256u + (unsigned)((k ^ (lane & 7)) << 4);

    f32x4 eA[16], eB[16];
    float t0, t1, t2, t3;
    float acc = 0.0f;

    // prologue: buf0 <- E(0), buf1 <- E(1); ids 2,3 resolved; eA <- buf0
    const int id0 = bids[0], id1 = bids[1];
    int ida = bids[2];                   // id(s+2) for even steps
    int idb = bids[3];                   // id(s+3) for odd steps
    stage_T(embT, id0, es[0], lane);
    stage_T(embT, id1, es[1], lane);
    asm volatile("s_waitcnt vmcnt(16) lgkmcnt(0)" ::: "memory"); // buf0 + SMEM done
    __builtin_amdgcn_sched_barrier(0);
    DSR4(eA,0,"0");  DSR4(eA,1,"0");  DSR4(eA,2,"0");  DSR4(eA,3,"0");
    DSR4(eA,4,"0");  DSR4(eA,5,"0");  DSR4(eA,6,"0");  DSR4(eA,7,"0");
    DSR4(eA,8,"0");  DSR4(eA,9,"0");  DSR4(eA,10,"0"); DSR4(eA,11,"0");
    DSR4(eA,12,"0"); DSR4(eA,13,"0"); DSR4(eA,14,"0"); DSR4(eA,15,"0");

    float v0 = (lane == r) ? 1.0f : 0.0f;  // row r of identity

    for (int s = 0; s < SS; s += 2) {
        // even: chain E(s) from eA; prefetch eB <- buf1 (E(s+1));
        //       DMA buf0 <- E(s+2) [ida]; reload ida <- ids[s+4]
        STEP(eA, eB, "16384", es[0], ida, 4, (s != 0));
        // odd:  chain E(s+1) from eB; prefetch eA <- buf0 (E(s+2));
        //       DMA buf1 <- E(s+3) [idb]; reload idb <- ids[s+5]
        STEP(eB, eA, "0",     es[1], idb, 5, true);
    }

    v0 = host_cosf(acc);                 // final step's cos
    out[b * (DD * DD) + r * DD + lane] = v0;
}

extern "C" void kernel_launch(void* const* d_in, const int* in_sizes, int n_in,
                              void* d_out, int out_size, void* d_ws, size_t ws_size,
                              hipStream_t stream)
{
    const int*   ids = (const int*)  d_in[0];   // [B, S] int32
    const float* emb = (const float*)d_in[1];   // [V, D*D] f32
    float*       out = (float*)      d_out;     // [B, D, D] f32
    float*       embT = (float*)     d_ws;      // V*4096 floats (1.5 MB)

    const int V = in_sizes[1] / (DD * DD);

    transpose_kernel<<<dim3(V), dim3(256), 0, stream>>>(emb, embT);
    text2vec_kernel<<<dim3(BB * DD), dim3(DD), 0, stream>>>(ids, embT, out);
}

// Round 9
// 4114.529 us; speedup vs baseline: 1.6667x; 1.2750x over previous
//
#include <hip/hip_runtime.h>

// Text2Vec: ctx[b] = cos(ctx[b] @ emb[ids[b,s]]), s = 0..8191.
// 512 independent row-chains (8 batches x 64 rows), one wave per (b,row),
// lane c owns column c. Per step: acc = sum_j readlane(v,j)*E[j][c] with
// ascending j, single accumulator, v_fmac (== host fmaf chain bit-exactly);
// v = host_cosf(acc) (branchless glibc cosf replica, bit-exact since R1).
//
// R8: NO LDS. R7 showed the LDS round-trip (DMA write + b128 read + 2.7e8
// bank-conflict cycles) was the hot pipe. The table is pre-transposed once
// into d_ws as embT[id][k*256 + c*4 + q] = E[4k+q][c]; lane c's whole column
// is then 16 coalesced global_load_dwordx4 (1 KB/instr, L2-resident) landing
// straight in registers. Loads are volatile asm with "=v" f32x4 outputs into
// eA/eB double buffers -- regalloc CANNOT sink/rematerialize them (the
// VGPR=76/84/88 failure of R3-R5 is structurally impossible). vmcnt-only
// sync; ids pipelined 2 deep; readfirstlane -> scalar load base per step.

#define BB 8
#define SS 8192
#define DD 64

typedef __attribute__((ext_vector_type(4))) float f32x4;

// ---- branchless bit-exact replica of glibc sysdeps/ieee754/flt-32 cosf ----
__device__ __forceinline__ float host_cosf(float y)
{
#pragma clang fp contract(off)
    const double hpi_inv = 0x1.45F306DC9C883p+23;  // 2/pi * 2^24
    const double hpi     = 0x1.921FB54442D18p0;    // pi/2
    const double c0 = 0x1p0;
    const double c1 = -0x1.ffffffd0c621cp-2;
    const double c2 = 0x1.55553e1068f19p-5;
    const double c3 = -0x1.6c087e89a359dp-10;
    const double c4 = 0x1.99343027bf8c3p-16;
    const double s1 = -0x1.555545995a603p-3;
    const double s2 = 0x1.1107605230bc4p-7;
    const double s3 = -0x1.994eb3774cf24p-13;

    const double x = (double)y;

    double r  = x * hpi_inv;
    int    n  = (((int)r) + 0x800000) >> 24;
    double xr = fma(-(double)n, hpi, x);

    const int  mm   = (n + 1) & 3;
    const double s  = (mm == 1 || mm == 2) ? -1.0 : 1.0;
    const bool negt = (mm & 2) != 0;

    double x2  = xr * xr;
    double x4  = x2 * x2;
    double cc2 = fma(x2, c4, c3);
    double cc1 = fma(x2, c1, c0);
    double x6  = x4 * x2;
    double cp  = fma(x4, c2, cc1);
    float fcos = (float)fma(x6, cc2, cp);
    fcos = negt ? -fcos : fcos;

    double xs  = xr * s;
    double x3  = xs * x2;
    double sp1 = fma(x2, s3, s2);
    double x7  = x3 * x2;
    double sr  = fma(x3, s1, xs);
    float fsin = (float)fma(x7, sp1, sr);

    return (n & 1) ? fsin : fcos;
}

// one-time: embT[id][(j>>2)*256 + c*4 + (j&3)] = emb[id][j*64 + c].
// Lane c's 16B chunk k = {E[4k..4k+3][c]}; wave chunk-k reads are contiguous.
__global__ void transpose_kernel(const float* __restrict__ emb,
                                 float* __restrict__ embT)
{
    const int id = blockIdx.x;
    const int t  = threadIdx.x;                 // 256 threads
    const float* src = emb + (size_t)id * (DD * DD);
    float*       dst = embT + (size_t)id * (DD * DD);
#pragma unroll
    for (int kk = 0; kk < 16; ++kk) {
        const int lin = kk * 256 + t;           // j*64 + c
        const int j = lin >> 6, c = lin & 63;
        dst[(j >> 2) * 256 + c * 4 + (j & 3)] = src[lin];
    }
}

// 16 coalesced dwordx4 loads: EN[h*4+k] <- embT[id] bytes [lane*16 + (h*4+k)*1024]
// voffE[h] = lane*16 + h*4096 (13-bit signed imm offset caps at 4095)
#define GL4(EN, H, K, OFFS) \
    asm volatile("global_load_dwordx4 %0, %1, %2 offset:" OFFS \
                 : "=v"(EN[(H)*4+(K)]) : "v"(voffE[H]), "s"(pnext))

#define LOAD_E(EN) do { \
    GL4(EN,0,0,"0"); GL4(EN,0,1,"1024"); GL4(EN,0,2,"2048"); GL4(EN,0,3,"3072"); \
    GL4(EN,1,0,"0"); GL4(EN,1,1,"1024"); GL4(EN,1,2,"2048"); GL4(EN,1,3,"3072"); \
    GL4(EN,2,0,"0"); GL4(EN,2,1,"1024"); GL4(EN,2,2,"2048"); GL4(EN,2,3,"3072"); \
    GL4(EN,3,0,"0"); GL4(EN,3,1,"1024"); GL4(EN,3,2,"2048"); GL4(EN,3,3,"3072"); \
} while (0)

// v_readlane into rotating SGPR temp (lane index literal)
#define RL(T, JL) \
    asm volatile("v_readlane_b32 %0, %1, " JL : "=s"(T) : "v"(v0))
// acc += t * e   (src0=SGPR, src1=VGPR; == fmaf(v_j, e_j, acc) bit-exactly)
#define FM(T, E) \
    asm volatile("v_fmac_f32 %0, %1, %2" : "+v"(acc) : "s"(T), "v"(E))

// 4 j-steps: consumes e[4K..4K+3] with temps t0..t3; issues readlanes 4K+3..4K+6
#define G4(EC, K, A, B, C, D) \
    RL(t3, A); FM(t0, EC[K][0]); \
    RL(t0, B); FM(t1, EC[K][1]); \
    RL(t1, C); FM(t2, EC[K][2]); \
    RL(t2, D); FM(t3, EC[K][3]);

// One chain step. EC: current e-regs (loads drained by top vmcnt).
// EN: e-regs to prefetch for next step. SOFF: id lookahead offset.
#define STEP(EC, EN, SOFF, DOCOS) do { \
    asm volatile("s_waitcnt vmcnt(0)" ::: "memory");  /* EC loads + idv ready */ \
    __builtin_amdgcn_sched_barrier(0);                /* nothing sinks above */ \
    { \
        const unsigned sid = (unsigned)__builtin_amdgcn_readfirstlane(idv); \
        const float* pnext = embT + (size_t)sid * (DD * DD); \
        LOAD_E(EN); \
        unsigned voff_ = (unsigned)(((s + (SOFF)) & (SS - 1)) * 4); \
        asm volatile("global_load_dword %0, %1, %2" \
                     : "=v"(idv) : "v"(voff_), "s"(bids)); \
    } \
    __builtin_amdgcn_sched_barrier(0);                /* cos stays below issues */ \
    if (DOCOS) v0 = host_cosf(acc); \
    acc = 0.0f; \
    RL(t0,"0"); RL(t1,"1"); RL(t2,"2"); \
    G4(EC, 0, "3","4","5","6")     G4(EC, 1, "7","8","9","10") \
    G4(EC, 2, "11","12","13","14") G4(EC, 3, "15","16","17","18") \
    G4(EC, 4, "19","20","21","22") G4(EC, 5, "23","24","25","26") \
    G4(EC, 6, "27","28","29","30") G4(EC, 7, "31","32","33","34") \
    G4(EC, 8, "35","36","37","38") G4(EC, 9, "39","40","41","42") \
    G4(EC,10, "43","44","45","46") G4(EC,11, "47","48","49","50") \
    G4(EC,12, "51","52","53","54") G4(EC,13, "55","56","57","58") \
    G4(EC,14, "59","60","61","62") \
    RL(t3,"63"); FM(t0, EC[15][0]); FM(t1, EC[15][1]); \
    FM(t2, EC[15][2]); FM(t3, EC[15][3]); \
} while (0)

__global__ __launch_bounds__(64, 1)
void text2vec_kernel(const int* __restrict__ ids,
                     const float* __restrict__ embT,
                     float* __restrict__ out)
{
    // blk = r*8 + b: all 64 rows of chain b share an XCD (L2-resident E)
    const int blk  = blockIdx.x;
    const int b    = blk & 7;
    const int r    = blk >> 3;           // 0..63
    const int lane = threadIdx.x;        // column c

    const int* bids = ids + b * SS;

    unsigned voffE[4];
#pragma unroll
    for (int h = 0; h < 4; ++h)
        voffE[h] = (unsigned)lane * 16u + (unsigned)h * 4096u;

    f32x4 eA[16], eB[16];
    float t0, t1, t2, t3;
    float acc = 0.0f;
    int   idv;

    // prologue: eA <- E(ids[0]) (scalar id via SMEM); idv <- ids[1]
    {
        const unsigned sid = (unsigned)bids[0];
        const float* pnext = embT + (size_t)sid * (DD * DD);
        LOAD_E(eA);
        unsigned voff_ = 4u;   // ids[1]
        asm volatile("global_load_dword %0, %1, %2"
                     : "=v"(idv) : "v"(voff_), "s"(bids));
    }

    float v0 = (lane == r) ? 1.0f : 0.0f;  // row r of identity

    for (int s = 0; s < SS; s += 2) {
        // even: chain E(s) from eA; prefetch eB <- E(s+1) [idv]; idv <- ids[s+2]
        STEP(eA, eB, 2, (s != 0));
        // odd:  chain E(s+1) from eB; prefetch eA <- E(s+2) [idv]; idv <- ids[s+3]
        STEP(eB, eA, 3, true);
    }

    v0 = host_cosf(acc);                 // final step's cos
    out[b * (DD * DD) + r * DD + lane] = v0;
}

extern "C" void kernel_launch(void* const* d_in, const int* in_sizes, int n_in,
                              void* d_out, int out_size, void* d_ws, size_t ws_size,
                              hipStream_t stream)
{
    const int*   ids = (const int*)  d_in[0];   // [B, S] int32
    const float* emb = (const float*)d_in[1];   // [V, D*D] f32
    float*       out = (float*)      d_out;     // [B, D, D] f32
    float*       embT = (float*)     d_ws;      // V*4096 floats (1.5 MB)

    const int V = in_sizes[1] / (DD * DD);

    transpose_kernel<<<dim3(V), dim3(256), 0, stream>>>(emb, embT);
    text2vec_kernel<<<dim3(BB * DD), dim3(DD), 0, stream>>>(ids, embT, out);
}

// Round 14
// 4034.041 us; speedup vs baseline: 1.6999x; 1.0200x over previous
//
#include <hip/hip_runtime.h>

// Text2Vec: ctx[b] = cos(ctx[b] @ emb[ids[b,s]]), s = 0..8191.
// 512 independent row-chains (8 batches x 64 rows), one wave per (b,row),
// lane c owns column c. Per step: acc = sum_j readlane(v,j)*E[j][c] with
// ascending j, single accumulator, v_fmac (== host fmaf chain bit-exactly);
// v = host_cosf(acc) (branchless glibc cosf replica, bit-exact since R1).
// Table pre-transposed once into d_ws (R8): lane c's column = 16 coalesced
// global_load_dwordx4 straight into registers; eA/eB double buffer, volatile
// asm so regalloc can't sink it. NO LDS.
//
// R13 isolation result: R8 (loads ALL at step top) passed; R10/R11/R12 (8
// loads moved mid-chain) all failed absmax=2.0 across THREE different id
// schemes, including R12's provably-safe compiler-managed s_load id. =>
// the mid-chain placement is the poison: interleaving 8 async "=v" defs into
// the highest-interference region (EC reads + f64 cos temps) breaks phi
// coalescing for the loop-carried eA/eB values, and regalloc's inserted
// v_movs copy in-flight load destinations before the data lands.
// R13 = R8's exact top-of-step load burst + R12's C++ id stream (id in lgkm
// domain: the step-top vmcnt(0) no longer tails on the id by construction).

#define BB 8
#define SS 8192
#define DD 64

typedef __attribute__((ext_vector_type(4))) float f32x4;

// ---- branchless bit-exact replica of glibc sysdeps/ieee754/flt-32 cosf ----
__device__ __forceinline__ float host_cosf(float y)
{
#pragma clang fp contract(off)
    const double hpi_inv = 0x1.45F306DC9C883p+23;  // 2/pi * 2^24
    const double hpi     = 0x1.921FB54442D18p0;    // pi/2
    const double c0 = 0x1p0;
    const double c1 = -0x1.ffffffd0c621cp-2;
    const double c2 = 0x1.55553e1068f19p-5;
    const double c3 = -0x1.6c087e89a359dp-10;
    const double c4 = 0x1.99343027bf8c3p-16;
    const double s1 = -0x1.555545995a603p-3;
    const double s2 = 0x1.1107605230bc4p-7;
    const double s3 = -0x1.994eb3774cf24p-13;

    const double x = (double)y;

    double r  = x * hpi_inv;
    int    n  = (((int)r) + 0x800000) >> 24;
    double xr = fma(-(double)n, hpi, x);

    const int  mm   = (n + 1) & 3;
    const double s  = (mm == 1 || mm == 2) ? -1.0 : 1.0;
    const bool negt = (mm & 2) != 0;

    double x2  = xr * xr;
    double x4  = x2 * x2;
    double cc2 = fma(x2, c4, c3);
    double cc1 = fma(x2, c1, c0);
    double x6  = x4 * x2;
    double cp  = fma(x4, c2, cc1);
    float fcos = (float)fma(x6, cc2, cp);
    fcos = negt ? -fcos : fcos;

    double xs  = xr * s;
    double x3  = xs * x2;
    double sp1 = fma(x2, s3, s2);
    double x7  = x3 * x2;
    double sr  = fma(x3, s1, xs);
    float fsin = (float)fma(x7, sp1, sr);

    return (n & 1) ? fsin : fcos;
}

// one-time: embT[id][(j>>2)*256 + c*4 + (j&3)] = emb[id][j*64 + c].
// Lane c's 16B chunk k = {E[4k..4k+3][c]}; wave chunk-k reads are contiguous.
__global__ void transpose_kernel(const float* __restrict__ emb,
                                 float* __restrict__ embT)
{
    const int id = blockIdx.x;
    const int t  = threadIdx.x;                 // 256 threads
    const float* src = emb + (size_t)id * (DD * DD);
    float*       dst = embT + (size_t)id * (DD * DD);
#pragma unroll
    for (int kk = 0; kk < 16; ++kk) {
        const int lin = kk * 256 + t;           // j*64 + c
        const int j = lin >> 6, c = lin & 63;
        dst[(j >> 2) * 256 + c * 4 + (j & 3)] = src[lin];
    }
}

// coalesced dwordx4: EN[h*4+k] <- embT[id] bytes [lane*16 + h*4096 + k*1024]
#define GL4(EN, H, K, OFFS) \
    asm volatile("global_load_dwordx4 %0, %1, %2 offset:" OFFS \
                 : "=v"(EN[(H)*4+(K)]) : "v"(voffE[H]), "s"(pnext))

#define GL4H(EN, H) \
    GL4(EN,H,0,"0"); GL4(EN,H,1,"1024"); GL4(EN,H,2,"2048"); GL4(EN,H,3,"3072")

// v_readlane into rotating SGPR temp (lane index literal)
#define RL(T, JL) \
    asm volatile("v_readlane_b32 %0, %1, " JL : "=s"(T) : "v"(v0))
// acc += t * e   (src0=SGPR, src1=VGPR; == fmaf(v_j, e_j, acc) bit-exactly)
#define FM(T, E) \
    asm volatile("v_fmac_f32 %0, %1, %2" : "+v"(acc) : "s"(T), "v"(E))

// 4 j-steps: consumes e[4K..4K+3] with temps t0..t3; issues readlanes 4K+3..4K+6
#define G4(EC, K, A, B, C, D) \
    RL(t3, A); FM(t0, EC[K][0]); \
    RL(t0, B); FM(t1, EC[K][1]); \
    RL(t1, C); FM(t2, EC[K][2]); \
    RL(t2, D); FM(t3, EC[K][3]);

// One chain step, R8 structure: ALL 16 E-loads issued in one burst at step
// top (low-interference window -> eA/eB phi coalesces, no v_mov of in-flight
// regs), then cos, then the pure-VALU chain. EC: current e-regs (drained by
// top vmcnt). EN: prefetch target. IDV: compiler-managed id (s_load, lgkm
// domain), holds the id for EN's prefetch; refilled SOFF ahead for use one
// iteration later.
#define STEP(EC, EN, IDV, SOFF, DOCOS) do { \
    const int idf_ = bids[(s + (SOFF)) & (SS - 1)];   /* compiler s_load */ \
    asm volatile("s_waitcnt vmcnt(0)" ::: "memory");  /* EC E-loads ready */ \
    __builtin_amdgcn_sched_barrier(0); \
    const unsigned sid = (unsigned)__builtin_amdgcn_readfirstlane(IDV); \
    const float* pnext = embT + (size_t)sid * (DD * DD); \
    GL4H(EN, 0); GL4H(EN, 1); GL4H(EN, 2); GL4H(EN, 3); \
    __builtin_amdgcn_sched_barrier(0);                /* cos stays below */ \
    if (DOCOS) v0 = host_cosf(acc);                   /* covers load latency */ \
    acc = 0.0f; \
    RL(t0,"0"); RL(t1,"1"); RL(t2,"2"); \
    G4(EC, 0, "3","4","5","6")     G4(EC, 1, "7","8","9","10") \
    G4(EC, 2, "11","12","13","14") G4(EC, 3, "15","16","17","18") \
    G4(EC, 4, "19","20","21","22") G4(EC, 5, "23","24","25","26") \
    G4(EC, 6, "27","28","29","30") G4(EC, 7, "31","32","33","34") \
    G4(EC, 8, "35","36","37","38") G4(EC, 9, "39","40","41","42") \
    G4(EC,10, "43","44","45","46") G4(EC,11, "47","48","49","50") \
    G4(EC,12, "51","52","53","54") G4(EC,13, "55","56","57","58") \
    G4(EC,14, "59","60","61","62") \
    RL(t3,"63"); FM(t0, EC[15][0]); FM(t1, EC[15][1]); \
    FM(t2, EC[15][2]); FM(t3, EC[15][3]); \
    IDV = idf_; \
} while (0)

__global__ __launch_bounds__(64, 1)
void text2vec_kernel(const int* __restrict__ ids,
                     const float* __restrict__ embT,
                     float* __restrict__ out)
{
    // blk = r*8 + b: all 64 rows of chain b share an XCD (L2-resident E)
    const int blk  = blockIdx.x;
    const int b    = blk & 7;
    const int r    = blk >> 3;           // 0..63
    const int lane = threadIdx.x;        // column c

    const int* bids = ids + b * SS;

    unsigned voffE[4];
#pragma unroll
    for (int h = 0; h < 4; ++h)
        voffE[h] = (unsigned)lane * 16u + (unsigned)h * 4096u;

    f32x4 eA[16], eB[16];
    float t0, t1, t2, t3;
    float acc = 0.0f;

    // id pipeline: all compiler-managed scalar loads (correct by construction)
    int idA = bids[1];                   // id for even-step prefetch (E(s+1))
    int idB = bids[2];                   // id for odd-step prefetch  (E(s+2))

    // prologue: eA <- E(ids[0]); readfirstlane guarantees SGPR for "s"(pnext)
    {
        const unsigned sid = (unsigned)__builtin_amdgcn_readfirstlane(bids[0]);
        const float* pnext = embT + (size_t)sid * (DD * DD);
        GL4H(eA, 0); GL4H(eA, 1); GL4H(eA, 2); GL4H(eA, 3);
    }

    float v0 = (lane == r) ? 1.0f : 0.0f;  // row r of identity

    for (int s = 0; s < SS; s += 2) {
        // even: chain E(s) from eA; prefetch eB <- E[idA]=E(s+1); idA <- ids[s+3]
        STEP(eA, eB, idA, 3, (s != 0));
        // odd:  chain E(s+1) from eB; prefetch eA <- E[idB]=E(s+2); idB <- ids[s+4]
        STEP(eB, eA, idB, 4, true);
    }

    v0 = host_cosf(acc);                 // final step's cos
    out[b * (DD * DD) + r * DD + lane] = v0;
}

extern "C" void kernel_launch(void* const* d_in, const int* in_sizes, int n_in,
                              void* d_out, int out_size, void* d_ws, size_t ws_size,
                              hipStream_t stream)
{
    const int*   ids = (const int*)  d_in[0];   // [B, S] int32
    const float* emb = (const float*)d_in[1];   // [V, D*D] f32
    float*       out = (float*)      d_out;     // [B, D, D] f32
    float*       embT = (float*)     d_ws;      // V*4096 floats (1.5 MB)

    const int V = in_sizes[1] / (DD * DD);

    transpose_kernel<<<dim3(V), dim3(256), 0, stream>>>(emb, embT);
    text2vec_kernel<<<dim3(BB * DD), dim3(DD), 0, stream>>>(ids, embT, out);
}